// Round 6
// baseline (611.423 us; speedup 1.0000x reference)
//
#include <hip/hip_runtime.h>

// Problem constants
#define BB  2
#define SS  2048
#define DD  2048
#define HH  16
#define HDD 128
#define BSR 4096   // BB*SS rows

using short8  = __attribute__((ext_vector_type(8))) short;
using floatx4 = __attribute__((ext_vector_type(4))) float;

__device__ __forceinline__ float bf2f(unsigned short u) {
  return __uint_as_float(((unsigned int)u) << 16);
}
__device__ __forceinline__ unsigned short f2bf(float f) {
  unsigned int u = __float_as_uint(f);
  u += 0x7fffu + ((u >> 16) & 1u);   // round-to-nearest-even
  return (unsigned short)(u >> 16);
}
// pack two floats -> two bf16 (rne) in one u32 (a=low, b=high)
__device__ __forceinline__ unsigned int pk2bf(float a, float b) {
  unsigned int ua = __float_as_uint(a);
  ua += 0x7fffu + ((ua >> 16) & 1u);
  unsigned int ub = __float_as_uint(b);
  ub += 0x7fffu + ((ub >> 16) & 1u);
  return (ua >> 16) | (ub & 0xffff0000u);
}
// fast 2^x (scores are kept in log2 domain)
__device__ __forceinline__ float fexp2(float x) {
#if __has_builtin(__builtin_amdgcn_exp2f)
  return __builtin_amdgcn_exp2f(x);
#else
  return __expf(x * 0.6931471805599453f);
#endif
}
// async global->LDS, 16 bytes per lane. LDS dest must be wave-uniform base + lane*16.
__device__ __forceinline__ void gl_lds16(const void* g, void* l) {
  __builtin_amdgcn_global_load_lds(
      (__attribute__((address_space(1))) void*)g,
      (__attribute__((address_space(3))) void*)l, 16, 0, 0);
}

// ---------------- prep: W transpose (bf16) + x convert + rope table, ONE launch -------
// blocks [0,4096): 64x64 W-transpose tiles (4 matrices x 1024 tiles)
// blocks [4096,12288): x fp32 -> bf16 (float4/thread)
// blocks [12288,12800): rope cos/sin table
__global__ __launch_bounds__(256) void prep(
    const float* __restrict__ x,
    const float* __restrict__ Wq, const float* __restrict__ Wk,
    const float* __restrict__ Wv, const float* __restrict__ Wo,
    unsigned short* __restrict__ xb, unsigned short* __restrict__ wqkvt,
    unsigned short* __restrict__ wot, float2* __restrict__ rtab)
{
  __shared__ unsigned short tr[64 * 66];
  int bx = blockIdx.x, t = threadIdx.x;
  if (bx < 4096) {
    int z = bx >> 10, tt = bx & 1023;
    int d0 = (tt >> 5) * 64, f0 = (tt & 31) * 64;
    const float* W = z == 0 ? Wq : (z == 1 ? Wk : (z == 2 ? Wv : Wo));
    unsigned short* Out = z < 3 ? wqkvt + (size_t)z * DD * DD : wot;
#pragma unroll
    for (int i = 0; i < 4; i++) {
      int r = (t >> 4) + i * 16;
      int col = (t & 15) * 4;
      float4 v = *(const float4*)&W[(size_t)(d0 + r) * DD + f0 + col];
      tr[(col + 0) * 66 + r] = f2bf(v.x);
      tr[(col + 1) * 66 + r] = f2bf(v.y);
      tr[(col + 2) * 66 + r] = f2bf(v.z);
      tr[(col + 3) * 66 + r] = f2bf(v.w);
    }
    __syncthreads();
#pragma unroll
    for (int i = 0; i < 8; i++) {
      int f = (t >> 5) + i * 8;
      int c = (t & 31) * 2;
      unsigned int u = *(const unsigned int*)&tr[f * 66 + c];
      *(unsigned int*)&Out[(size_t)(f0 + f) * DD + d0 + c] = u;
    }
  } else if (bx < 12288) {
    size_t i = ((size_t)(bx - 4096) * 256 + t) * 4;
    float4 v = *(const float4*)(x + i);
    ushort4 o;
    o.x = f2bf(v.x); o.y = f2bf(v.y); o.z = f2bf(v.z); o.w = f2bf(v.w);
    *(ushort4*)(xb + i) = o;
  } else {
    int idx = (bx - 12288) * 256 + t;
    int s = idx >> 6, c = idx & 63;
    float inv = powf(10000.f, -(float)c * (1.f / 64.f));
    float ang = (float)s * inv;
    float sn, cc;
    sincosf(ang, &sn, &cc);
    rtab[idx] = make_float2(cc, sn);
  }
}

// ---------------- fused QKV GEMM + bias + RoPE + V-transpose ----------------
// C[4096,6144] = xb * wqkvt^T. 128x128 tile == one (plane, head) column block.
// LDS capped at 32768B (As|Bs; epilogue reuses As region as 64x132 half-tile,
// two passes) -> 5 blocks/CU with __launch_bounds__(256,5).
__global__ __launch_bounds__(256, 5) void gemm_qkv(
    const unsigned short* __restrict__ A, const unsigned short* __restrict__ Bt,
    const float* __restrict__ bq, const float* __restrict__ bk,
    const float* __restrict__ bv, const float2* __restrict__ rtab,
    unsigned short* __restrict__ q_r, unsigned short* __restrict__ k_r,
    unsigned short* __restrict__ v_t)
{
  __shared__ unsigned short smem[16384];   // As(8192)|Bs(8192); epilogue: Ct64[64][132]
  unsigned short* As = smem;
  unsigned short* Bs = smem + 8192;
  const int K = DD;
  int t = threadIdx.x;
  int m0 = blockIdx.y * 128, n0 = blockIdx.x * 128;
  int w = t >> 6, lane = t & 63, qd = lane >> 4, l16 = lane & 15;
  int wm = (w >> 1) * 64, wn = (w & 1) * 64;
  floatx4 zero4 = {0.f, 0.f, 0.f, 0.f};
  floatx4 acc[4][4];
#pragma unroll
  for (int i = 0; i < 4; i++)
#pragma unroll
    for (int j = 0; j < 4; j++) acc[i][j] = zero4;

  int gchunk = (t & 7) ^ ((t >> 3) & 7);
  const unsigned short* Ab = A  + (size_t)(m0 + (t >> 3)) * K + gchunk * 8;
  const unsigned short* Bb = Bt + (size_t)(n0 + (t >> 3)) * K + gchunk * 8;
  size_t qK = (size_t)32 * K;

  for (int k0 = 0; k0 < K; k0 += 64) {
    __syncthreads();
#pragma unroll
    for (int c = 0; c < 4; c++) {
      gl_lds16(Ab + c * qK + k0, &As[(c * 256 + t) * 8]);
      gl_lds16(Bb + c * qK + k0, &Bs[(c * 256 + t) * 8]);
    }
    __syncthreads();
#pragma unroll
    for (int ks = 0; ks < 2; ks++) {
      int ch = ((ks * 4 + qd) ^ (l16 & 7)) * 8;
      short8 af[4], bfr[4];
#pragma unroll
      for (int i = 0; i < 4; i++)
        af[i] = *(const short8*)&As[(wm + i * 16 + l16) * 64 + ch];
#pragma unroll
      for (int j = 0; j < 4; j++)
        bfr[j] = *(const short8*)&Bs[(wn + j * 16 + l16) * 64 + ch];
#pragma unroll
      for (int i = 0; i < 4; i++)
#pragma unroll
        for (int j = 0; j < 4; j++)
          acc[i][j] = __builtin_amdgcn_mfma_f32_16x16x32_bf16(af[i], bfr[j], acc[i][j], 0, 0, 0);
    }
  }

  // ---- two-pass epilogue (64 rows at a time through smem Ct64, stride 132) ----
  int plane = n0 >> 11;            // 0=q, 1=k, 2=v
  int h = (n0 >> 7) & 15;
  const float* bias = plane == 0 ? bq : (plane == 1 ? bk : bv);
  int b = m0 >> 11, sbase = m0 & (SS - 1);
  const float fac = (plane == 0) ? 0.12751744f : 1.0f;   // 1/sqrt(128)*log2(e) for q

  for (int half = 0; half < 2; half++) {
    __syncthreads();               // As/Bs (or previous half's Ct) reads done
    if ((w >> 1) == half) {
#pragma unroll
      for (int i = 0; i < 4; i++)
#pragma unroll
        for (int j = 0; j < 4; j++) {
          int cl = wn + j * 16 + l16;
          float bsv = bias[h * 128 + cl];
#pragma unroll
          for (int r = 0; r < 4; r++)
            smem[(i * 16 + qd * 4 + r) * 132 + cl] = f2bf(acc[i][j][r] + bsv);
        }
    }
    __syncthreads();

    if (plane < 2) {
      unsigned short* dst = (plane == 0 ? q_r : k_r) + (size_t)(b * HH + h) * SS * HDD;
#pragma unroll
      for (int it = 0; it < 8; it++) {
        int idx = it * 256 + t;
        int rl = idx >> 5, c2 = (idx & 31) * 2;
        int s = sbase + half * 64 + rl;
        float4 cs = *(const float4*)&rtab[(size_t)s * 64 + c2];
        float a0 = bf2f(smem[rl * 132 + c2]);
        float a1 = bf2f(smem[rl * 132 + c2 + 1]);
        float b0 = bf2f(smem[rl * 132 + c2 + 64]);
        float b1 = bf2f(smem[rl * 132 + c2 + 65]);
        unsigned int lo = pk2bf((a0 * cs.x - b0 * cs.y) * fac,
                                (a1 * cs.z - b1 * cs.w) * fac);
        unsigned int hi = pk2bf((a0 * cs.y + b0 * cs.x) * fac,
                                (a1 * cs.w + b1 * cs.z) * fac);
        size_t rowb = (size_t)s * HDD;
        *(unsigned int*)&dst[rowb + c2]      = lo;
        *(unsigned int*)&dst[rowb + c2 + 64] = hi;
      }
    } else {
      // v: transpose to [hd][s] with kappa key-permute within each 64-block
      unsigned short* dst = v_t + (size_t)(b * HH + h) * HDD * SS;
#pragma unroll
      for (int it = 0; it < 16; it++) {
        int idx = it * 256 + t;
        int hd = idx >> 5, sp = (idx & 31) * 2;
        unsigned short v0 = smem[sp * 132 + hd];
        unsigned short v1 = smem[(sp + 1) * 132 + hd];
        int kap = ((sp >> 5) & 1) * 32 + ((sp >> 2) & 3) * 8 + ((sp >> 4) & 1) * 4 + (sp & 3);
        int sg = sbase + half * 64 + kap;
        *(unsigned int*)&dst[(size_t)hd * SS + sg] = ((unsigned int)v1 << 16) | v0;
      }
    }
  }
}

// ---------------- final projection GEMM: 128x64 tiles for 4 blocks/CU -----------
// C[M,N] = A[M,K] * Bt[N,K]^T + bias, fp32 out. 1024 blocks (was 512 at 128x128).
__global__ __launch_bounds__(256, 4) void gemm_o(
    const unsigned short* __restrict__ A, const unsigned short* __restrict__ Bt,
    const float* __restrict__ bias, float* __restrict__ Cout)
{
  __shared__ unsigned short As[128 * 64];   // 16 KB
  __shared__ unsigned short Bs[64 * 64];    // 8 KB
  const int K = DD, N = DD;
  int t = threadIdx.x;
  int m0 = blockIdx.y * 128, n0 = blockIdx.x * 64;
  int w = t >> 6, lane = t & 63, qd = lane >> 4, l16 = lane & 15;
  int wm = (w >> 1) * 64, wn = (w & 1) * 32;
  floatx4 zero4 = {0.f, 0.f, 0.f, 0.f};
  floatx4 acc[4][2];
#pragma unroll
  for (int i = 0; i < 4; i++)
#pragma unroll
    for (int j = 0; j < 2; j++) acc[i][j] = zero4;

  int gchunk = (t & 7) ^ ((t >> 3) & 7);
  const unsigned short* Ab = A  + (size_t)(m0 + (t >> 3)) * K + gchunk * 8;
  const unsigned short* Bb = Bt + (size_t)(n0 + (t >> 3)) * K + gchunk * 8;
  size_t qK = (size_t)32 * K;

  for (int k0 = 0; k0 < K; k0 += 64) {
    __syncthreads();
#pragma unroll
    for (int c = 0; c < 4; c++)
      gl_lds16(Ab + c * qK + k0, &As[(c * 256 + t) * 8]);
#pragma unroll
    for (int c = 0; c < 2; c++)
      gl_lds16(Bb + c * qK + k0, &Bs[(c * 256 + t) * 8]);
    __syncthreads();
#pragma unroll
    for (int ks = 0; ks < 2; ks++) {
      int ch = ((ks * 4 + qd) ^ (l16 & 7)) * 8;
      short8 af[4], bfr[2];
#pragma unroll
      for (int i = 0; i < 4; i++)
        af[i] = *(const short8*)&As[(wm + i * 16 + l16) * 64 + ch];
#pragma unroll
      for (int j = 0; j < 2; j++)
        bfr[j] = *(const short8*)&Bs[(wn + j * 16 + l16) * 64 + ch];
#pragma unroll
      for (int i = 0; i < 4; i++)
#pragma unroll
        for (int j = 0; j < 2; j++)
          acc[i][j] = __builtin_amdgcn_mfma_f32_16x16x32_bf16(af[i], bfr[j], acc[i][j], 0, 0, 0);
    }
  }

#pragma unroll
  for (int i = 0; i < 4; i++)
#pragma unroll
    for (int j = 0; j < 2; j++) {
      int row = m0 + wm + i * 16 + qd * 4;
      int col = n0 + wn + j * 16 + l16;
      float bsv = bias[col];
#pragma unroll
      for (int r = 0; r < 4; r++)
        Cout[(size_t)(row + r) * N + col] = acc[i][j][r] + bsv;
    }
}

// ---------------- flash attention v5: dbuf staging + XCD swizzle + exp2 ----------
__global__ __launch_bounds__(256, 2) void attn_kernel(
    const unsigned short* __restrict__ q_r, const unsigned short* __restrict__ k_r,
    const unsigned short* __restrict__ v_t, unsigned short* __restrict__ aout)
{
  __shared__ unsigned short Ks[2][64 * 128];   // [key][hd], swizzled chunks
  __shared__ unsigned short Vs[2][128 * 64];   // [hd][key-slot], swizzled chunks
  int t = threadIdx.x, w = t >> 6, lane = t & 63, qd = lane >> 4, l16 = lane & 15;
  int L = blockIdx.y * gridDim.x + blockIdx.x;
  int jj = L >> 3;
  int bh = (L & 7) * 4 + (jj >> 4);
  int q0 = (jj & 15) * 128;
  const unsigned short* qb = q_r + (size_t)bh * SS * HDD;
  const unsigned short* kb = k_r + (size_t)bh * SS * HDD;
  const unsigned short* vb = v_t + (size_t)bh * HDD * SS;

  short8 aq[2][4];
#pragma unroll
  for (int mi = 0; mi < 2; mi++)
#pragma unroll
    for (int ks = 0; ks < 4; ks++)
      aq[mi][ks] = *(const short8*)
          &qb[(size_t)(q0 + w * 32 + mi * 16 + l16) * HDD + ks * 32 + qd * 8];

  float m_i[2], l_i[2];
  floatx4 zero4 = {0.f, 0.f, 0.f, 0.f};
  floatx4 o[2][8];
#pragma unroll
  for (int mi = 0; mi < 2; mi++) { m_i[mi] = -1e30f; l_i[mi] = 0.f; }
#pragma unroll
  for (int mi = 0; mi < 2; mi++)
#pragma unroll
    for (int n = 0; n < 8; n++) o[mi][n] = zero4;

  auto stage = [&](int nb, int kt) {
#pragma unroll
    for (int c = 0; c < 4; c++) {
      int flat = c * 256 + t;
      int r = flat >> 4, cc = flat & 15;
      gl_lds16(kb + (size_t)(kt + r) * HDD + (cc ^ (r & 15)) * 8, &Ks[nb][flat * 8]);
    }
#pragma unroll
    for (int c = 0; c < 4; c++) {
      int flat = c * 256 + t;
      int r = flat >> 3, cc = flat & 7;
      gl_lds16(vb + (size_t)r * SS + kt + (cc ^ (r & 7)) * 8, &Vs[nb][flat * 8]);
    }
  };

  stage(0, 0);
  int buf = 0;

  for (int kt = 0; kt < SS; kt += 64) {
    __syncthreads();
    if (kt + 64 < SS) stage(buf ^ 1, kt + 64);

    floatx4 sc[2][4];
#pragma unroll
    for (int mi = 0; mi < 2; mi++)
#pragma unroll
      for (int j = 0; j < 4; j++) sc[mi][j] = zero4;
#pragma unroll
    for (int j = 0; j < 4; j++) {
      int krow = j * 16 + l16;
#pragma unroll
      for (int ks = 0; ks < 4; ks++) {
        int chunk = ks * 4 + qd;
        short8 kf = *(const short8*)&Ks[buf][krow * 128 + ((chunk ^ (krow & 15)) * 8)];
        sc[0][j] = __builtin_amdgcn_mfma_f32_16x16x32_bf16(kf, aq[0][ks], sc[0][j], 0, 0, 0);
        sc[1][j] = __builtin_amdgcn_mfma_f32_16x16x32_bf16(kf, aq[1][ks], sc[1][j], 0, 0, 0);
      }
    }

    float rmax[2];
#pragma unroll
    for (int mi = 0; mi < 2; mi++) {
      float m = sc[mi][0][0];
#pragma unroll
      for (int j = 0; j < 4; j++)
#pragma unroll
        for (int r = 0; r < 4; r++) m = fmaxf(m, sc[mi][j][r]);
      m = fmaxf(m, __shfl_xor(m, 16, 64));
      m = fmaxf(m, __shfl_xor(m, 32, 64));
      rmax[mi] = m;
    }

    bool up = (rmax[0] > m_i[0]) || (rmax[1] > m_i[1]);
    if (__ballot(up) != 0ull) {
#pragma unroll
      for (int mi = 0; mi < 2; mi++) {
        float mn = fmaxf(m_i[mi], rmax[mi]);
        float a = fexp2(m_i[mi] - mn);
        m_i[mi] = mn;
        l_i[mi] *= a;
#pragma unroll
        for (int n = 0; n < 8; n++)
#pragma unroll
          for (int r = 0; r < 4; r++) o[mi][n][r] *= a;
      }
    }

    unsigned int pr[2][4][2];
#pragma unroll
    for (int mi = 0; mi < 2; mi++) {
      float s0 = 0.f;
#pragma unroll
      for (int j = 0; j < 4; j++) {
        float p0 = fexp2(sc[mi][j][0] - m_i[mi]);
        float p1 = fexp2(sc[mi][j][1] - m_i[mi]);
        float p2 = fexp2(sc[mi][j][2] - m_i[mi]);
        float p3 = fexp2(sc[mi][j][3] - m_i[mi]);
        s0 += (p0 + p1) + (p2 + p3);
        pr[mi][j][0] = pk2bf(p0, p1);
        pr[mi][j][1] = pk2bf(p2, p3);
      }
      s0 += __shfl_xor(s0, 16, 64);
      s0 += __shfl_xor(s0, 32, 64);
      l_i[mi] += s0;
    }

#pragma unroll
    for (int n = 0; n < 8; n++) {
      int vrow = n * 16 + l16;
#pragma unroll
      for (int ks = 0; ks < 2; ks++) {
        int chunk = ks * 4 + qd;
        short8 av = *(const short8*)&Vs[buf][vrow * 64 + ((chunk ^ (vrow & 7)) * 8)];
        union { unsigned int u[4]; short8 v; } bp0, bp1;
        bp0.u[0] = pr[0][2 * ks][0];     bp0.u[1] = pr[0][2 * ks][1];
        bp0.u[2] = pr[0][2 * ks + 1][0]; bp0.u[3] = pr[0][2 * ks + 1][1];
        bp1.u[0] = pr[1][2 * ks][0];     bp1.u[1] = pr[1][2 * ks][1];
        bp1.u[2] = pr[1][2 * ks + 1][0]; bp1.u[3] = pr[1][2 * ks + 1][1];
        o[0][n] = __builtin_amdgcn_mfma_f32_16x16x32_bf16(av, bp0.v, o[0][n], 0, 0, 0);
        o[1][n] = __builtin_amdgcn_mfma_f32_16x16x32_bf16(av, bp1.v, o[1][n], 0, 0, 0);
      }
    }
    buf ^= 1;
  }

  int b = bh >> 4, h = bh & 15;
#pragma unroll
  for (int mi = 0; mi < 2; mi++) {
    int qrow = q0 + w * 32 + mi * 16 + l16;
    float inv_l = 1.f / l_i[mi];
    size_t base = ((size_t)(b * SS + qrow)) * DD + h * HDD;
#pragma unroll
    for (int n = 0; n < 8; n++) {
      uint2 pkd;
      pkd.x = pk2bf(o[mi][n][0] * inv_l, o[mi][n][1] * inv_l);
      pkd.y = pk2bf(o[mi][n][2] * inv_l, o[mi][n][3] * inv_l);
      *(uint2*)&aout[base + n * 16 + qd * 4] = pkd;
    }
  }
}

// ---------------- launch ----------------
extern "C" void kernel_launch(void* const* d_in, const int* in_sizes, int n_in,
                              void* d_out, int out_size, void* d_ws, size_t ws_size,
                              hipStream_t stream) {
  const float* x  = (const float*)d_in[0];
  const float* Wq = (const float*)d_in[1];
  const float* bq = (const float*)d_in[2];
  const float* Wk = (const float*)d_in[3];
  const float* bk = (const float*)d_in[4];
  const float* Wv = (const float*)d_in[5];
  const float* bv = (const float*)d_in[6];
  const float* Wo = (const float*)d_in[7];
  const float* bo = (const float*)d_in[8];
  float* out = (float*)d_out;

  char* ws = (char*)d_ws;
  unsigned short* xb      = (unsigned short*)(ws + 0);            // [BS,D] bf16, 16 MB
  unsigned short* wqkvt   = (unsigned short*)(ws + 16777216);     // [3D,D] bf16, 24 MB
  unsigned short* wot     = (unsigned short*)(ws + 41943040);     // [D,D]  bf16, 8 MB
  float2*         rtab    = (float2*)(ws + 50331648);             // [S,64] f32x2, 1 MB
  unsigned short* q_r     = (unsigned short*)(ws + 100663296);    // [B,H,S,HD] 16 MB
  unsigned short* k_r     = (unsigned short*)(ws + 117440512);    // [B,H,S,HD] 16 MB
  unsigned short* v_t     = (unsigned short*)(ws + 134217728);    // [B,H,HD,S] 16 MB
  unsigned short* attn_o  = xb;   // alias: xb dead after gemm_qkv

  prep<<<dim3(12800), dim3(256), 0, stream>>>(
      x, Wq, Wk, Wv, Wo, xb, wqkvt, wot, rtab);
  gemm_qkv<<<dim3(3 * DD / 128, BSR / 128), dim3(256), 0, stream>>>(
      xb, wqkvt, bq, bk, bv, rtab, q_r, k_r, v_t);
  attn_kernel<<<dim3(SS / 128, BB * HH), dim3(256), 0, stream>>>(
      q_r, k_r, v_t, attn_o);
  gemm_o<<<dim3(DD / 64, BSR / 128), dim3(256), 0, stream>>>(
      attn_o, wot, bo, out);
}